// Round 11
// baseline (375.162 us; speedup 1.0000x reference)
//
#include <hip/hip_runtime.h>
#include <math.h>

#define BB 8
#define CCH 256
#define NN 16384
#define KK 64
#define SEGS 64        // 64 segments x 256 n

typedef __attribute__((ext_vector_type(8))) short bf16x8;
typedef __attribute__((ext_vector_type(4))) float f32x4;
#define MFMA16 __builtin_amdgcn_mfma_f32_16x16x32_bf16

// ---------------- workspace layout (float-slot offsets) ----------------
constexpr size_t OFF_ATTN = 0;                        // bf16 B*N*K  = 4194304 slots
constexpr size_t OFF_CTT  = 4194304;                  // bf16 K*C    = 8192 slots (16384 reserved)
constexpr size_t OFF_PWT  = 4210688;                  // f32 C*C     = 65536
constexpr size_t OFF_GT   = 4276224;                  // bf16 B*C*K  = 65536 slots
constexpr size_t OFF_CLUP = 4341760;                  // bf16 SEGS*B*K*C = 4194304 slots
constexpr size_t OFF_MP   = 8536064;                  // bf16 SEGS*B*K*K = 1048576 slots
constexpr size_t OFF_ABP  = 9584640;                  // f32 SEGS*B*K = 32768
constexpr size_t OFF_CLUS = 9617408;                  // f32 B*K*C    = 131072
constexpr size_t OFF_MS2  = 9748480;                  // f32 B*K*K    = 32768
constexpr size_t OFF_ABS2 = 9781248;                  // f32 B*K      = 512
constexpr size_t OFF_QP   = 9781760;                  // f32 B*8*C    = 16384
// CLUP region is dead after p15 -> reuse for post-reduce buffers:
constexpr size_t OFF_REF  = OFF_CLUP;                 // f32 B*K*C  (dead after p2_g)
constexpr size_t OFF_G    = OFF_CLUP + 131072;        // f32 B*K*C
constexpr size_t OFF_MU   = OFF_CLUP + 262144;        // f32 B*32
constexpr size_t OFF_RS   = OFF_CLUP + 262400;        // f32 B*32
// total = 9,798,144 slots = 39.2 MB

__device__ __forceinline__ unsigned short f2bf(float f) {
    unsigned int x = __float_as_uint(f);
    unsigned int r = (x + 0x7FFFu + ((x >> 16) & 1u)) >> 16;
    return (unsigned short)r;
}
__device__ __forceinline__ float bf2f(unsigned short u) {
    return __uint_as_float(((unsigned int)u) << 16);
}

// ---------- P0: centers -> bf16 (scale 2^-4 folded, exact), transpose pw_w ----------
__global__ __launch_bounds__(256) void p0_prep(const float* __restrict__ centers,
                                               const float* __restrict__ pw_w,
                                               float* __restrict__ ws) {
    int idx = blockIdx.x * 256 + threadIdx.x;   // 0..65535
    if (idx < 16384)
        ((unsigned short*)(ws + OFF_CTT))[idx] = f2bf(centers[idx] * 0.0625f);
    int c = idx >> 8, o = idx & 255;
    ws[OFF_PWT + idx] = pw_w[o * CCH + c];
}

// ---------- P1: MFMA sim^T -> in-register softmax -> attn(bf16) ; MFMA cluster/M ----------
// R10 traffic/occupancy constants (SEGS=64, LDS 59392, bounds(256,2)).
// Single change vs R10: sim computed TRANSPOSED (A=centers, B=x^T) so each lane
// holds a full 64-k column of S for one n -> softmax is in-register (2 shfl_xor),
// removing the S LDS round-trip and 2 barriers per sub-tile (30 -> 22 per block).
__global__ __launch_bounds__(256, 2) void p1_attn(const float* __restrict__ x,
                                                  float* __restrict__ ws) {
    __shared__ __align__(16) unsigned char smem[59392];
    // [0,32768): xs bf16 [256][64], byte ^= ((c&7)<<4) swizzle ; epilogue: CLUP staging
    unsigned short* xTh = (unsigned short*)(smem + 32768); // bf16 [64][136] (c-half)
    float*          S   = (float*)(smem + 32768);          // f32 [64][68] (epilogue M staging)
    unsigned short* aT  = (unsigned short*)(smem + 50176); // bf16 [64][72] attn^T
    float*          scr = (float*)(smem + 50176);          // abar scratch (aT dead)

    const int tid = threadIdx.x;
    const int w  = tid >> 6;       // wave 0..3
    const int l  = tid & 63;
    const int lr = l & 15;
    const int lg = l >> 4;
    const int b   = blockIdx.y;
    const int seg = blockIdx.x;    // 0..63
    const int cstage = tid >> 4;   // 0..15
    const int n4     = tid & 15;

    const unsigned short* ctb = (const unsigned short*)(ws + OFF_CTT);
    unsigned short* attn_bf = (unsigned short*)(ws + OFF_ATTN);

    f32x4 cacc[4][4] = {};   // cluster [kt][ct], c-strip = w*64..
    f32x4 macc[4]    = {};   // M [k1t], k2-strip = w*16..
    float ab_acc = 0.f;

    float4 v[8];
    {   // preload sub0 half0
#pragma unroll
        for (int it = 0; it < 8; ++it) {
            int c = it * 16 + cstage;
            v[it] = *(const float4*)&x[((size_t)(b * CCH + c)) * NN + seg * 256 + 4 * n4];
        }
    }

#pragma unroll 1
    for (int sub = 0; sub < 4; ++sub) {
        const int ns0 = seg * 256 + sub * 64;
        f32x4 sacc[4] = {};   // S^T tiles: [kt]; lane holds n=16w+lr, k=kt*16+lg*4+r

#pragma unroll
        for (int h = 0; h < 2; ++h) {
            __syncthreads();   // prev consumers of xs/xTh done
#pragma unroll
            for (int it = 0; it < 8; ++it) {
                int c = h * 128 + it * 16 + cstage;
                int cl = c & 127;
                ushort4 bv;
                bv.x = f2bf(v[it].x); bv.y = f2bf(v[it].y);
                bv.z = f2bf(v[it].z); bv.w = f2bf(v[it].w);
                *(ushort4*)(smem + ((c * 128 + 8 * n4) ^ ((c & 7) << 4))) = bv;
                xTh[(4 * n4 + 0) * 136 + cl] = bv.x;
                xTh[(4 * n4 + 1) * 136 + cl] = bv.y;
                xTh[(4 * n4 + 2) * 136 + cl] = bv.z;
                xTh[(4 * n4 + 3) * 136 + cl] = bv.w;
            }
            if (!(sub == 3 && h == 1)) {
                const int nsub = sub + h;
                const int nh = h ^ 1;
                const int pns0 = seg * 256 + nsub * 64;
#pragma unroll
                for (int it = 0; it < 8; ++it) {
                    int c = nh * 128 + it * 16 + cstage;
                    v[it] = *(const float4*)&x[((size_t)(b * CCH + c)) * NN + pns0 + 4 * n4];
                }
            }
            __syncthreads();
#pragma unroll
            for (int cc = 0; cc < 4; ++cc) {
                const int co = cc * 32 + lg * 8;
                // B-frag: x^T rows (this wave's n-block), c-contiguous
                bf16x8 bx = *(const bf16x8*)(xTh + (w * 16 + lr) * 136 + co);
                // A-frags: centers rows (all 4 k-tiles), L1-hot global
                const unsigned short* cbase = ctb + (h * 4 + cc) * 32 + lg * 8;
                bf16x8 c0 = *(const bf16x8*)(cbase + (size_t)(0 * 16 + lr) * CCH);
                bf16x8 c1 = *(const bf16x8*)(cbase + (size_t)(1 * 16 + lr) * CCH);
                bf16x8 c2 = *(const bf16x8*)(cbase + (size_t)(2 * 16 + lr) * CCH);
                bf16x8 c3 = *(const bf16x8*)(cbase + (size_t)(3 * 16 + lr) * CCH);
                sacc[0] = MFMA16(c0, bx, sacc[0], 0, 0, 0);
                sacc[1] = MFMA16(c1, bx, sacc[1], 0, 0, 0);
                sacc[2] = MFMA16(c2, bx, sacc[2], 0, 0, 0);
                sacc[3] = MFMA16(c3, bx, sacc[3], 0, 0, 0);
            }
        }

        // ---- in-register softmax over k (column n = 16w+lr per lane) ----
        {
            float mx = -1e30f;
#pragma unroll
            for (int kt = 0; kt < 4; ++kt)
#pragma unroll
                for (int r = 0; r < 4; ++r) mx = fmaxf(mx, sacc[kt][r]);
            mx = fmaxf(mx, __shfl_xor(mx, 16, 64));
            mx = fmaxf(mx, __shfl_xor(mx, 32, 64));
            f32x4 e[4];
            float ls = 0.f;
#pragma unroll
            for (int kt = 0; kt < 4; ++kt)
#pragma unroll
                for (int r = 0; r < 4; ++r) {
                    float ev = __expf(sacc[kt][r] - mx);
                    e[kt][r] = ev;
                    ls += ev;
                }
            ls += __shfl_xor(ls, 16, 64);
            ls += __shfl_xor(ls, 32, 64);
            float rinv = 1.f / ls;
#pragma unroll
            for (int kt = 0; kt < 4; ++kt)
#pragma unroll
                for (int r = 0; r < 4; ++r)
                    aT[(kt * 16 + lg * 4 + r) * 72 + w * 16 + lr] = f2bf(e[kt][r] * rinv);
        }
        __syncthreads();   // aT ready

        // ---- coalesced global attn write (read-back from aT) ----
        {
            const int rn = tid >> 2, q = tid & 3;
            unsigned short t16[16];
#pragma unroll
            for (int j = 0; j < 16; ++j)
                t16[j] = aT[(q * 16 + j) * 72 + rn];
            uint4 pk0, pk1;
            pk0.x = (unsigned int)t16[0]  | ((unsigned int)t16[1]  << 16);
            pk0.y = (unsigned int)t16[2]  | ((unsigned int)t16[3]  << 16);
            pk0.z = (unsigned int)t16[4]  | ((unsigned int)t16[5]  << 16);
            pk0.w = (unsigned int)t16[6]  | ((unsigned int)t16[7]  << 16);
            pk1.x = (unsigned int)t16[8]  | ((unsigned int)t16[9]  << 16);
            pk1.y = (unsigned int)t16[10] | ((unsigned int)t16[11] << 16);
            pk1.z = (unsigned int)t16[12] | ((unsigned int)t16[13] << 16);
            pk1.w = (unsigned int)t16[14] | ((unsigned int)t16[15] << 16);
            unsigned int* gdst = (unsigned int*)(attn_bf + ((size_t)b * NN + ns0 + rn) * KK + q * 16);
            *(uint4*)gdst = pk0;
            *(uint4*)(gdst + 4) = pk1;
        }

        // ---- abar partial ----
        {
            const int kk = tid & 63;
#pragma unroll
            for (int m = 0; m < 4; ++m) {
                ushort4 av = *(const ushort4*)(aT + kk * 72 + w * 16 + 4 * m);
                ab_acc += bf2f(av.x) + bf2f(av.y) + bf2f(av.z) + bf2f(av.w);
            }
        }
        // ---- M partial ----
#pragma unroll
        for (int s = 0; s < 2; ++s) {
            const int no = s * 32 + lg * 8;
            bf16x8 am = *(const bf16x8*)(aT + (w * 16 + lr) * 72 + no);
#pragma unroll
            for (int k1t = 0; k1t < 4; ++k1t) {
                bf16x8 bm = *(const bf16x8*)(aT + (k1t * 16 + lr) * 72 + no);
                macc[k1t] = MFMA16(am, bm, macc[k1t], 0, 0, 0);
            }
        }
        // ---- CLU partial ----
#pragma unroll
        for (int s = 0; s < 2; ++s) {
            const int no = s * 32 + lg * 8;
            bf16x8 aa0 = *(const bf16x8*)(aT + (lr     ) * 72 + no);
            bf16x8 aa1 = *(const bf16x8*)(aT + (16 + lr) * 72 + no);
            bf16x8 aa2 = *(const bf16x8*)(aT + (32 + lr) * 72 + no);
            bf16x8 aa3 = *(const bf16x8*)(aT + (48 + lr) * 72 + no);
#pragma unroll
            for (int ct = 0; ct < 4; ++ct) {
                const int c = w * 64 + ct * 16 + lr;
                bf16x8 bb = *(const bf16x8*)(smem + ((c * 128 + no * 2) ^ ((c & 7) << 4)));
                cacc[0][ct] = MFMA16(aa0, bb, cacc[0][ct], 0, 0, 0);
                cacc[1][ct] = MFMA16(aa1, bb, cacc[1][ct], 0, 0, 0);
                cacc[2][ct] = MFMA16(aa2, bb, cacc[2][ct], 0, 0, 0);
                cacc[3][ct] = MFMA16(aa3, bb, cacc[3][ct], 0, 0, 0);
            }
        }
    }

    // ---- epilogue: stage CLUP (bf16, xs region) + M (S region) + abar (scr) ----
    __syncthreads();   // all xs/aT/S reads complete
    {
        unsigned short* stg = (unsigned short*)smem;   // [64 k][256 c], c ^= ((k&7)<<3)
#pragma unroll
        for (int kt = 0; kt < 4; ++kt)
#pragma unroll
            for (int ct = 0; ct < 4; ++ct) {
                const int c = w * 64 + ct * 16 + lr;
#pragma unroll
                for (int r = 0; r < 4; ++r) {
                    const int row = kt * 16 + lg * 4 + r;
                    stg[row * 256 + (c ^ ((row & 7) << 3))] = f2bf(cacc[kt][ct][r]);
                }
            }
    }
#pragma unroll
    for (int k1t = 0; k1t < 4; ++k1t)
#pragma unroll
        for (int r = 0; r < 4; ++r)
            S[(w * 16 + lg * 4 + r) * 68 + k1t * 16 + lr] = macc[k1t][r];
    scr[(tid & 63) * 4 + (tid >> 6)] = ab_acc;
    __syncthreads();
    // ---- coalesced global writes ----
    {
        uint4* gb = (uint4*)((unsigned short*)(ws + OFF_CLUP) + (size_t)(seg * BB + b) * 16384);
        const uint4* s4 = (const uint4*)smem;
#pragma unroll
        for (int it = 0; it < 8; ++it) {
            int f = it * 256 + tid;                    // 0..2047
            gb[f] = s4[(f >> 5) * 32 + ((f & 31) ^ ((f >> 5) & 7))];
        }
    }
    {
        unsigned int* mp32 = (unsigned int*)((unsigned short*)(ws + OFF_MP) + (size_t)(seg * BB + b) * 4096);
#pragma unroll
        for (int it = 0; it < 8; ++it) {
            int flat = it * 256 + tid;                 // 0..2047
            int k2 = flat >> 5, kp = flat & 31;
            unsigned int pv = (unsigned int)f2bf(S[k2 * 68 + 2 * kp])
                            | ((unsigned int)f2bf(S[k2 * 68 + 2 * kp + 1]) << 16);
            mp32[flat] = pv;
        }
    }
    if (tid < 64)
        ws[OFF_ABP + (size_t)(seg * BB + b) * KK + tid] =
            scr[tid * 4 + 0] + scr[tid * 4 + 1] + scr[tid * 4 + 2] + scr[tid * 4 + 3];
}

// ---------- P1.5: reduce partials over 64 segs ----------
__global__ __launch_bounds__(256) void p15_reduce(float* __restrict__ ws) {
    const int blk = blockIdx.x;
    if (blk < 512) {
        const int b = blk >> 6, k = blk & 63, c = threadIdx.x;
        const unsigned short* clu_p = (const unsigned short*)(ws + OFF_CLUP);
        float s = 0.f;
#pragma unroll 8
        for (int seg = 0; seg < SEGS; ++seg)
            s += bf2f(clu_p[((size_t)((seg * BB + b) * KK + k)) * CCH + c]);
        ws[OFF_CLUS + ((size_t)(b * KK + k)) * CCH + c] = s;
    } else {
        const int t = blk - 512;
        const int b = t >> 3, part = t & 7;
        const unsigned short* m_p = (const unsigned short*)(ws + OFF_MP);
#pragma unroll
        for (int it = 0; it < 2; ++it) {
            int idx = part * 512 + it * 256 + threadIdx.x;
            float s = 0.f;
#pragma unroll 8
            for (int seg = 0; seg < SEGS; ++seg)
                s += bf2f(m_p[(size_t)(seg * BB + b) * 4096 + idx]);
            ws[OFF_MS2 + (size_t)b * 4096 + idx] = s;
        }
        if (part == 0 && threadIdx.x < 64) {
            float s = 0.f;
#pragma unroll 8
            for (int seg = 0; seg < SEGS; ++seg)
                s += ws[OFF_ABP + (size_t)(seg * BB + b) * KK + threadIdx.x];
            ws[OFF_ABS2 + b * KK + threadIdx.x] = s;
        }
    }
}

// ---------- P2a: depthwise 7x7 + bias + silu on 8x8 cluster grid ----------
__global__ __launch_bounds__(256) void p2_dw(const float* __restrict__ dw_w,
                                             const float* __restrict__ dw_b,
                                             float* __restrict__ ws) {
    __shared__ float clu_s[64][256];
    const int b = blockIdx.y;
    const int kq = blockIdx.x;
    const int tid = threadIdx.x;
    float* ref = ws + OFF_REF;

    for (int k = 0; k < 64; ++k)
        clu_s[k][tid] = ws[OFF_CLUS + ((size_t)(b * KK + k)) * CCH + tid];
    float w[49];
#pragma unroll
    for (int t = 0; t < 49; ++t) w[t] = dw_w[tid * 49 + t];
    float bias = dw_b[tid];
    __syncthreads();

    for (int it = 0; it < 16; ++it) {
        int k = kq * 16 + it;
        int ky = k >> 3, kx = k & 7;
        float v = 0.f;
#pragma unroll
        for (int dy = 0; dy < 7; ++dy) {
            int yy = ky + dy - 3;
            if (yy < 0 || yy > 7) continue;
#pragma unroll
            for (int dx = 0; dx < 7; ++dx) {
                int xx = kx + dx - 3;
                if (xx < 0 || xx > 7) continue;
                v += clu_s[yy * 8 + xx][tid] * w[dy * 7 + dx];
            }
        }
        v += bias;
        float sv = v / (1.f + expf(-v));
        ref[((size_t)b * KK + k) * CCH + tid] = sv;
    }
}

// ---------- P2b: G[b,k,o] = sum_c refined * pw_w[o,c] + pw_b[o]; also G^T bf16 ----------
__global__ __launch_bounds__(256) void p2_g(const float* __restrict__ pw_b,
                                            float* __restrict__ ws) {
    __shared__ float rs[256];
    const int b = blockIdx.y, k = blockIdx.x, tid = threadIdx.x;
    const float* ref = ws + OFF_REF;
    const float* pwT = ws + OFF_PWT;
    float* G = ws + OFF_G;
    rs[tid] = ref[((size_t)b * KK + k) * CCH + tid];
    __syncthreads();
    float g = pw_b[tid];
#pragma unroll 8
    for (int c = 0; c < 256; ++c)
        g += rs[c] * pwT[c * CCH + tid];
    G[((size_t)b * KK + k) * CCH + tid] = g;
    ((unsigned short*)(ws + OFF_GT))[((size_t)b * CCH + tid) * KK + k] = f2bf(g);
}

// ---------- P2w: qpart[b,kq,c] = sum_{kk<8} W[kq*8+kk,c] * G[kq*8+kk,c] ----------
__global__ __launch_bounds__(256) void p2_w(float* __restrict__ ws) {
    __shared__ float Mrows[512];     // 8 k-rows of M, pre-scaled
    const int kq = blockIdx.x, b = blockIdx.y;
    const int tid = threadIdx.x;
#pragma unroll
    for (int it = 0; it < 2; ++it) {
        int idx = it * 256 + tid;    // 0..511
        Mrows[idx] = ws[OFF_MS2 + (size_t)b * 4096 + kq * 512 + idx] * (1.0f / 16384.0f);
    }
    __syncthreads();
    const float* G = ws + OFF_G + (size_t)b * KK * CCH;
    float t0 = 0.f, t1 = 0.f, t2 = 0.f, t3 = 0.f;
    float t4 = 0.f, t5 = 0.f, t6 = 0.f, t7 = 0.f;
#pragma unroll 8
    for (int k2 = 0; k2 < 64; ++k2) {
        float g = G[k2 * CCH + tid];
        t0 += Mrows[0 * 64 + k2] * g;
        t1 += Mrows[1 * 64 + k2] * g;
        t2 += Mrows[2 * 64 + k2] * g;
        t3 += Mrows[3 * 64 + k2] * g;
        t4 += Mrows[4 * 64 + k2] * g;
        t5 += Mrows[5 * 64 + k2] * g;
        t6 += Mrows[6 * 64 + k2] * g;
        t7 += Mrows[7 * 64 + k2] * g;
    }
    const float* Gk = G + (size_t)(kq * 8) * CCH + tid;
    float qp = t0 * Gk[0 * CCH] + t1 * Gk[1 * CCH] + t2 * Gk[2 * CCH] + t3 * Gk[3 * CCH]
             + t4 * Gk[4 * CCH] + t5 * Gk[5 * CCH] + t6 * Gk[6 * CCH] + t7 * Gk[7 * CCH];
    ws[OFF_QP + (size_t)(b * 8 + kq) * CCH + tid] = qp;
}

// ---------- P2c: group-norm statistics (mu from G stream, q from qpart) ----------
__global__ __launch_bounds__(256) void p2_stats(float* __restrict__ ws) {
    __shared__ float abs_[64];
    __shared__ float mu_s[256];
    __shared__ float q_s[256];
    const int b = blockIdx.x, tid = threadIdx.x;
    if (tid < 64)
        abs_[tid] = ws[OFF_ABS2 + b * KK + tid] * (1.0f / 16384.0f);
    __syncthreads();

    const float* G = ws + OFF_G + (size_t)b * KK * CCH;
    float mu = 0.f;
#pragma unroll 8
    for (int k = 0; k < 64; ++k)
        mu += abs_[k] * G[(size_t)k * CCH + tid];
    const float* qp = ws + OFF_QP + (size_t)b * 8 * CCH + tid;
    float q = 0.f;
#pragma unroll
    for (int kq = 0; kq < 8; ++kq)
        q += qp[(size_t)kq * CCH];
    mu_s[tid] = mu;
    q_s[tid] = q;
    __syncthreads();
    if (tid < 32) {
        float m = 0.f, e = 0.f;
#pragma unroll
        for (int j = 0; j < 8; ++j) { m += mu_s[tid * 8 + j]; e += q_s[tid * 8 + j]; }
        m *= 0.125f; e *= 0.125f;
        float var = e - m * m;
        ws[OFF_MU + b * 32 + tid] = m;
        ws[OFF_RS + b * 32 + tid] = rsqrtf(fmaxf(var, 0.f) + 1e-5f);
    }
}

// ---------- P3: y = attn @ G via MFMA ; out = x + (y-mu)*rsig*gamma + beta ----------
// GT fragments loaded direct global->reg (L2-hot); only attn staged in LDS (8 KB).
__global__ __launch_bounds__(256, 3) void p3_out(const float* __restrict__ x,
                                                 const float* __restrict__ gamma,
                                                 const float* __restrict__ beta,
                                                 const float* __restrict__ ws,
                                                 float* __restrict__ out) {
    __shared__ __align__(16) unsigned char sm3[8192];
    // attn tile bf16 [64 n][64 k], byte ^= ((n&7)<<4)
    const int tid = threadIdx.x;
    const int w  = tid >> 6;
    const int l  = tid & 63;
    const int lr = l & 15;
    const int lg = l >> 4;
    const int n0 = blockIdx.x * 64;
    const int b  = blockIdx.y;

    const unsigned short* attn_bf = (const unsigned short*)(ws + OFF_ATTN);
    const unsigned short* GTb = (const unsigned short*)(ws + OFF_GT) + (size_t)b * CCH * KK;

    // GT fragments: issue before the LDS barrier (hide L2 latency under staging)
    bf16x8 bg0[4], bg1[4];
#pragma unroll
    for (int ot = 0; ot < 4; ++ot) {
        const int o = w * 64 + ot * 16 + lr;
        bg0[ot] = *(const bf16x8*)(GTb + (size_t)o * KK + 0 * 32 + lg * 8);
        bg1[ot] = *(const bf16x8*)(GTb + (size_t)o * KK + 1 * 32 + lg * 8);
    }

    {
        const uint4* asrc = (const uint4*)(attn_bf + ((size_t)b * NN + n0) * KK);
#pragma unroll
        for (int it = 0; it < 2; ++it) {
            int flat = it * 256 + tid;
            int n = flat >> 3, c16 = flat & 7;
            *(uint4*)(sm3 + ((n * 128 + c16 * 16) ^ ((n & 7) << 4))) = asrc[n * 8 + c16];
        }
    }
    __syncthreads();

    f32x4 acc[4][4] = {};   // [nt][ot]
#pragma unroll
    for (int kh = 0; kh < 2; ++kh) {
        bf16x8 af[4];
#pragma unroll
        for (int nt = 0; nt < 4; ++nt) {
            int n = nt * 16 + lr;
            af[nt] = *(const bf16x8*)(sm3 + ((n * 128 + (kh * 64 + lg * 16)) ^ ((n & 7) << 4)));
        }
#pragma unroll
        for (int nt = 0; nt < 4; ++nt)
#pragma unroll
            for (int ot = 0; ot < 4; ++ot)
                acc[nt][ot] = MFMA16(af[nt], kh ? bg1[ot] : bg0[ot], acc[nt][ot], 0, 0, 0);
    }

#pragma unroll
    for (int ot = 0; ot < 4; ++ot) {
        const int o = w * 64 + ot * 16 + lr;
        const int grp = o >> 3;
        const float m = ws[OFF_MU + b * 32 + grp];
        const float r = ws[OFF_RS + b * 32 + grp];
        const float gm = gamma[o] * r;
        const float bt = beta[o];
#pragma unroll
        for (int nt = 0; nt < 4; ++nt) {
            const int n = n0 + nt * 16 + lg * 4;
            size_t base = ((size_t)(b * CCH + o)) * NN + n;
            float4 xv = *(const float4*)&x[base];
            f32x4 a = acc[nt][ot];
            float4 ov;
            ov.x = xv.x + (a[0] - m) * gm + bt;
            ov.y = xv.y + (a[1] - m) * gm + bt;
            ov.z = xv.z + (a[2] - m) * gm + bt;
            ov.w = xv.w + (a[3] - m) * gm + bt;
            *(float4*)&out[base] = ov;
        }
    }
}

extern "C" void kernel_launch(void* const* d_in, const int* in_sizes, int n_in,
                              void* d_out, int out_size, void* d_ws, size_t ws_size,
                              hipStream_t stream) {
    (void)in_sizes; (void)n_in; (void)out_size; (void)ws_size;
    const float* x       = (const float*)d_in[0];
    const float* centers = (const float*)d_in[1];
    const float* dw_w    = (const float*)d_in[2];
    const float* dw_b    = (const float*)d_in[3];
    const float* pw_w    = (const float*)d_in[4];
    const float* pw_b    = (const float*)d_in[5];
    const float* gn_g    = (const float*)d_in[6];
    const float* gn_b    = (const float*)d_in[7];
    float* out = (float*)d_out;
    float* ws  = (float*)d_ws;

    p0_prep<<<256, 256, 0, stream>>>(centers, pw_w, ws);
    p1_attn<<<dim3(64, 8), 256, 0, stream>>>(x, ws);
    p15_reduce<<<576, 256, 0, stream>>>(ws);
    p2_dw<<<dim3(4, 8), 256, 0, stream>>>(dw_w, dw_b, ws);
    p2_g<<<dim3(64, 8), 256, 0, stream>>>(pw_b, ws);
    p2_w<<<dim3(8, 8), 256, 0, stream>>>(ws);
    p2_stats<<<8, 256, 0, stream>>>(ws);
    p3_out<<<dim3(256, 8), 256, 0, stream>>>(x, gn_g, gn_b, ws, out);
}

// Round 12
// 346.406 us; speedup vs baseline: 1.0830x; 1.0830x over previous
//
#include <hip/hip_runtime.h>
#include <math.h>

#define BB 8
#define CCH 256
#define NN 16384
#define KK 64
#define SEGS 64        // 64 segments x 256 n

typedef __attribute__((ext_vector_type(8))) short bf16x8;
typedef __attribute__((ext_vector_type(4))) float f32x4;
#define MFMA16 __builtin_amdgcn_mfma_f32_16x16x32_bf16

// ---------------- workspace layout (float-slot offsets) ----------------
constexpr size_t OFF_ATTN = 0;                        // bf16 B*N*K  = 4194304 slots
constexpr size_t OFF_CTT  = 4194304;                  // bf16 K*C    = 8192 slots (16384 reserved)
constexpr size_t OFF_PWT  = 4210688;                  // f32 C*C     = 65536
constexpr size_t OFF_GT   = 4276224;                  // bf16 B*C*K  = 65536 slots
constexpr size_t OFF_CLUP = 4341760;                  // bf16 SEGS*B*K*C = 4194304 slots
constexpr size_t OFF_MP   = 8536064;                  // bf16 SEGS*B*K*K = 1048576 slots
constexpr size_t OFF_ABP  = 9584640;                  // f32 SEGS*B*K = 32768
constexpr size_t OFF_CLUS = 9617408;                  // f32 B*K*C    = 131072
constexpr size_t OFF_MS2  = 9748480;                  // f32 B*K*K    = 32768
constexpr size_t OFF_ABS2 = 9781248;                  // f32 B*K      = 512
constexpr size_t OFF_QP   = 9781760;                  // f32 B*8*C    = 16384
// CLUP region is dead after p15 -> reuse for post-reduce buffers:
constexpr size_t OFF_REF  = OFF_CLUP;                 // f32 B*K*C  (dead after p2_g)
constexpr size_t OFF_G    = OFF_CLUP + 131072;        // f32 B*K*C
constexpr size_t OFF_MU   = OFF_CLUP + 262144;        // f32 B*32
constexpr size_t OFF_RS   = OFF_CLUP + 262400;        // f32 B*32
// total = 9,798,144 slots = 39.2 MB

__device__ __forceinline__ unsigned short f2bf(float f) {
    unsigned int x = __float_as_uint(f);
    unsigned int r = (x + 0x7FFFu + ((x >> 16) & 1u)) >> 16;
    return (unsigned short)r;
}
__device__ __forceinline__ float bf2f(unsigned short u) {
    return __uint_as_float(((unsigned int)u) << 16);
}

// ---------- P0: centers -> bf16 (scale 2^-4 folded, exact), transpose pw_w ----------
__global__ __launch_bounds__(256) void p0_prep(const float* __restrict__ centers,
                                               const float* __restrict__ pw_w,
                                               float* __restrict__ ws) {
    int idx = blockIdx.x * 256 + threadIdx.x;   // 0..65535
    if (idx < 16384)
        ((unsigned short*)(ws + OFF_CTT))[idx] = f2bf(centers[idx] * 0.0625f);
    int c = idx >> 8, o = idx & 255;
    ws[OFF_PWT + idx] = pw_w[o * CCH + c];
}

// ---------- P1: MFMA sim -> softmax(shfl) -> attn(bf16) ; MFMA cluster/M ----------
// R10-exact (best measured: 349 us total). SEGS=64, LDS 59392, bounds(256,2),
// hoisted centers frags, LDS softmax, bf16 CLUP epilogue.
__global__ __launch_bounds__(256, 2) void p1_attn(const float* __restrict__ x,
                                                  float* __restrict__ ws) {
    __shared__ __align__(16) unsigned char smem[59392];
    // [0,32768): xs bf16 [256][64], byte ^= ((c&7)<<4) swizzle ; epilogue: CLUP staging
    unsigned short* xTh = (unsigned short*)(smem + 32768); // bf16 [64][136] (c-half)
    float*          S   = (float*)(smem + 32768);          // f32 [64][68] overlay
    unsigned short* aT  = (unsigned short*)(smem + 50176); // bf16 [64][72] attn^T
    float*          scr = (float*)(smem + 50176);          // abar scratch (aT dead)

    const int tid = threadIdx.x;
    const int w  = tid >> 6;       // wave 0..3
    const int l  = tid & 63;
    const int lr = l & 15;
    const int lg = l >> 4;
    const int b   = blockIdx.y;
    const int seg = blockIdx.x;    // 0..63
    const int cstage = tid >> 4;   // 0..15
    const int n4     = tid & 15;

    const unsigned short* ctb = (const unsigned short*)(ws + OFF_CTT);
    unsigned short* attn_bf = (unsigned short*)(ws + OFF_ATTN);

    bf16x8 bc[8];
#pragma unroll
    for (int cs = 0; cs < 8; ++cs)
        bc[cs] = *(const bf16x8*)(ctb + (w * 16 + lr) * CCH + cs * 32 + lg * 8);

    f32x4 cacc[4][4] = {};   // cluster [kt][ct], c-strip = w*64..
    f32x4 macc[4]    = {};   // M [k1t], k2-strip = w*16..
    float ab_acc = 0.f;

    float4 v[8];
    {   // preload sub0 half0
#pragma unroll
        for (int it = 0; it < 8; ++it) {
            int c = it * 16 + cstage;
            v[it] = *(const float4*)&x[((size_t)(b * CCH + c)) * NN + seg * 256 + 4 * n4];
        }
    }

#pragma unroll 1
    for (int sub = 0; sub < 4; ++sub) {
        const int ns0 = seg * 256 + sub * 64;
        f32x4 sacc[4] = {};

#pragma unroll
        for (int h = 0; h < 2; ++h) {
            __syncthreads();   // prev consumers of xs/xTh done
#pragma unroll
            for (int it = 0; it < 8; ++it) {
                int c = h * 128 + it * 16 + cstage;
                int cl = c & 127;
                ushort4 bv;
                bv.x = f2bf(v[it].x); bv.y = f2bf(v[it].y);
                bv.z = f2bf(v[it].z); bv.w = f2bf(v[it].w);
                *(ushort4*)(smem + ((c * 128 + 8 * n4) ^ ((c & 7) << 4))) = bv;
                xTh[(4 * n4 + 0) * 136 + cl] = bv.x;
                xTh[(4 * n4 + 1) * 136 + cl] = bv.y;
                xTh[(4 * n4 + 2) * 136 + cl] = bv.z;
                xTh[(4 * n4 + 3) * 136 + cl] = bv.w;
            }
            if (!(sub == 3 && h == 1)) {
                const int nsub = sub + h;
                const int nh = h ^ 1;
                const int pns0 = seg * 256 + nsub * 64;
#pragma unroll
                for (int it = 0; it < 8; ++it) {
                    int c = nh * 128 + it * 16 + cstage;
                    v[it] = *(const float4*)&x[((size_t)(b * CCH + c)) * NN + pns0 + 4 * n4];
                }
            }
            __syncthreads();
#pragma unroll
            for (int cc = 0; cc < 4; ++cc) {
                const int co = cc * 32 + lg * 8;
                bf16x8 a0 = *(const bf16x8*)(xTh + (lr     ) * 136 + co);
                bf16x8 a1 = *(const bf16x8*)(xTh + (16 + lr) * 136 + co);
                bf16x8 a2 = *(const bf16x8*)(xTh + (32 + lr) * 136 + co);
                bf16x8 a3 = *(const bf16x8*)(xTh + (48 + lr) * 136 + co);
                bf16x8 bfr = bc[h * 4 + cc];
                sacc[0] = MFMA16(a0, bfr, sacc[0], 0, 0, 0);
                sacc[1] = MFMA16(a1, bfr, sacc[1], 0, 0, 0);
                sacc[2] = MFMA16(a2, bfr, sacc[2], 0, 0, 0);
                sacc[3] = MFMA16(a3, bfr, sacc[3], 0, 0, 0);
            }
        }
        __syncthreads();   // xTh reads done -> region becomes S
#pragma unroll
        for (int nt = 0; nt < 4; ++nt)
#pragma unroll
            for (int r = 0; r < 4; ++r)
                S[(nt * 16 + lg * 4 + r) * 68 + w * 16 + lr] = sacc[nt][r];
        __syncthreads();

        // ---- softmax: 4 lanes per row, shuffle reduce ----
        {
            const int rn = tid >> 2, q = tid & 3;
            float e[16];
#pragma unroll
            for (int m = 0; m < 4; ++m) {
                float4 vv = *(float4*)&S[rn * 68 + q * 16 + 4 * m];
                e[4*m+0] = vv.x; e[4*m+1] = vv.y; e[4*m+2] = vv.z; e[4*m+3] = vv.w;
            }
            float mx = -1e30f;
#pragma unroll
            for (int t = 0; t < 16; ++t) mx = fmaxf(mx, e[t]);
            mx = fmaxf(mx, __shfl_xor(mx, 1, 64));
            mx = fmaxf(mx, __shfl_xor(mx, 2, 64));
            float ls = 0.f;
#pragma unroll
            for (int t = 0; t < 16; ++t) { e[t] = __expf(e[t] - mx); ls += e[t]; }
            ls += __shfl_xor(ls, 1, 64);
            ls += __shfl_xor(ls, 2, 64);
            float rinv = 1.f / ls;
            unsigned short bt16[16];
#pragma unroll
            for (int t = 0; t < 16; ++t) {
                bt16[t] = f2bf(e[t] * rinv);
                aT[(q * 16 + t) * 72 + rn] = bt16[t];
            }
            unsigned int* gdst = (unsigned int*)(attn_bf + ((size_t)b * NN + ns0 + rn) * KK + q * 16);
            uint4 pk0, pk1;
            pk0.x = (unsigned int)bt16[0]  | ((unsigned int)bt16[1]  << 16);
            pk0.y = (unsigned int)bt16[2]  | ((unsigned int)bt16[3]  << 16);
            pk0.z = (unsigned int)bt16[4]  | ((unsigned int)bt16[5]  << 16);
            pk0.w = (unsigned int)bt16[6]  | ((unsigned int)bt16[7]  << 16);
            pk1.x = (unsigned int)bt16[8]  | ((unsigned int)bt16[9]  << 16);
            pk1.y = (unsigned int)bt16[10] | ((unsigned int)bt16[11] << 16);
            pk1.z = (unsigned int)bt16[12] | ((unsigned int)bt16[13] << 16);
            pk1.w = (unsigned int)bt16[14] | ((unsigned int)bt16[15] << 16);
            *(uint4*)gdst = pk0;
            *(uint4*)(gdst + 4) = pk1;
        }
        __syncthreads();   // aT ready

        // ---- abar partial ----
        {
            const int kk = tid & 63;
#pragma unroll
            for (int m = 0; m < 4; ++m) {
                ushort4 av = *(const ushort4*)(aT + kk * 72 + w * 16 + 4 * m);
                ab_acc += bf2f(av.x) + bf2f(av.y) + bf2f(av.z) + bf2f(av.w);
            }
        }
        // ---- M partial ----
#pragma unroll
        for (int s = 0; s < 2; ++s) {
            const int no = s * 32 + lg * 8;
            bf16x8 am = *(const bf16x8*)(aT + (w * 16 + lr) * 72 + no);
#pragma unroll
            for (int k1t = 0; k1t < 4; ++k1t) {
                bf16x8 bm = *(const bf16x8*)(aT + (k1t * 16 + lr) * 72 + no);
                macc[k1t] = MFMA16(am, bm, macc[k1t], 0, 0, 0);
            }
        }
        // ---- CLU partial ----
#pragma unroll
        for (int s = 0; s < 2; ++s) {
            const int no = s * 32 + lg * 8;
            bf16x8 aa0 = *(const bf16x8*)(aT + (lr     ) * 72 + no);
            bf16x8 aa1 = *(const bf16x8*)(aT + (16 + lr) * 72 + no);
            bf16x8 aa2 = *(const bf16x8*)(aT + (32 + lr) * 72 + no);
            bf16x8 aa3 = *(const bf16x8*)(aT + (48 + lr) * 72 + no);
#pragma unroll
            for (int ct = 0; ct < 4; ++ct) {
                const int c = w * 64 + ct * 16 + lr;
                bf16x8 bb = *(const bf16x8*)(smem + ((c * 128 + no * 2) ^ ((c & 7) << 4)));
                cacc[0][ct] = MFMA16(aa0, bb, cacc[0][ct], 0, 0, 0);
                cacc[1][ct] = MFMA16(aa1, bb, cacc[1][ct], 0, 0, 0);
                cacc[2][ct] = MFMA16(aa2, bb, cacc[2][ct], 0, 0, 0);
                cacc[3][ct] = MFMA16(aa3, bb, cacc[3][ct], 0, 0, 0);
            }
        }
    }

    // ---- epilogue: stage CLUP (bf16, xs region) + M (S region) + abar (scr) ----
    __syncthreads();   // all xs/aT/S reads complete
    {
        unsigned short* stg = (unsigned short*)smem;   // [64 k][256 c], c ^= ((k&7)<<3)
#pragma unroll
        for (int kt = 0; kt < 4; ++kt)
#pragma unroll
            for (int ct = 0; ct < 4; ++ct) {
                const int c = w * 64 + ct * 16 + lr;
#pragma unroll
                for (int r = 0; r < 4; ++r) {
                    const int row = kt * 16 + lg * 4 + r;
                    stg[row * 256 + (c ^ ((row & 7) << 3))] = f2bf(cacc[kt][ct][r]);
                }
            }
    }
#pragma unroll
    for (int k1t = 0; k1t < 4; ++k1t)
#pragma unroll
        for (int r = 0; r < 4; ++r)
            S[(w * 16 + lg * 4 + r) * 68 + k1t * 16 + lr] = macc[k1t][r];
    scr[(tid & 63) * 4 + (tid >> 6)] = ab_acc;
    __syncthreads();
    // ---- coalesced global writes ----
    {
        uint4* gb = (uint4*)((unsigned short*)(ws + OFF_CLUP) + (size_t)(seg * BB + b) * 16384);
        const uint4* s4 = (const uint4*)smem;
#pragma unroll
        for (int it = 0; it < 8; ++it) {
            int f = it * 256 + tid;                    // 0..2047
            gb[f] = s4[(f >> 5) * 32 + ((f & 31) ^ ((f >> 5) & 7))];
        }
    }
    {
        unsigned int* mp32 = (unsigned int*)((unsigned short*)(ws + OFF_MP) + (size_t)(seg * BB + b) * 4096);
#pragma unroll
        for (int it = 0; it < 8; ++it) {
            int flat = it * 256 + tid;                 // 0..2047
            int k2 = flat >> 5, kp = flat & 31;
            unsigned int pv = (unsigned int)f2bf(S[k2 * 68 + 2 * kp])
                            | ((unsigned int)f2bf(S[k2 * 68 + 2 * kp + 1]) << 16);
            mp32[flat] = pv;
        }
    }
    if (tid < 64)
        ws[OFF_ABP + (size_t)(seg * BB + b) * KK + tid] =
            scr[tid * 4 + 0] + scr[tid * 4 + 1] + scr[tid * 4 + 2] + scr[tid * 4 + 3];
}

// ---------- P1.5: reduce partials over 64 segs ----------
__global__ __launch_bounds__(256) void p15_reduce(float* __restrict__ ws) {
    const int blk = blockIdx.x;
    if (blk < 512) {
        const int b = blk >> 6, k = blk & 63, c = threadIdx.x;
        const unsigned short* clu_p = (const unsigned short*)(ws + OFF_CLUP);
        float s = 0.f;
#pragma unroll 8
        for (int seg = 0; seg < SEGS; ++seg)
            s += bf2f(clu_p[((size_t)((seg * BB + b) * KK + k)) * CCH + c]);
        ws[OFF_CLUS + ((size_t)(b * KK + k)) * CCH + c] = s;
    } else {
        const int t = blk - 512;
        const int b = t >> 3, part = t & 7;
        const unsigned short* m_p = (const unsigned short*)(ws + OFF_MP);
#pragma unroll
        for (int it = 0; it < 2; ++it) {
            int idx = part * 512 + it * 256 + threadIdx.x;
            float s = 0.f;
#pragma unroll 8
            for (int seg = 0; seg < SEGS; ++seg)
                s += bf2f(m_p[(size_t)(seg * BB + b) * 4096 + idx]);
            ws[OFF_MS2 + (size_t)b * 4096 + idx] = s;
        }
        if (part == 0 && threadIdx.x < 64) {
            float s = 0.f;
#pragma unroll 8
            for (int seg = 0; seg < SEGS; ++seg)
                s += ws[OFF_ABP + (size_t)(seg * BB + b) * KK + threadIdx.x];
            ws[OFF_ABS2 + b * KK + threadIdx.x] = s;
        }
    }
}

// ---------- P2a: depthwise 7x7 + bias + silu on 8x8 cluster grid ----------
__global__ __launch_bounds__(256) void p2_dw(const float* __restrict__ dw_w,
                                             const float* __restrict__ dw_b,
                                             float* __restrict__ ws) {
    __shared__ float clu_s[64][256];
    const int b = blockIdx.y;
    const int kq = blockIdx.x;
    const int tid = threadIdx.x;
    float* ref = ws + OFF_REF;

    for (int k = 0; k < 64; ++k)
        clu_s[k][tid] = ws[OFF_CLUS + ((size_t)(b * KK + k)) * CCH + tid];
    float w[49];
#pragma unroll
    for (int t = 0; t < 49; ++t) w[t] = dw_w[tid * 49 + t];
    float bias = dw_b[tid];
    __syncthreads();

    for (int it = 0; it < 16; ++it) {
        int k = kq * 16 + it;
        int ky = k >> 3, kx = k & 7;
        float v = 0.f;
#pragma unroll
        for (int dy = 0; dy < 7; ++dy) {
            int yy = ky + dy - 3;
            if (yy < 0 || yy > 7) continue;
#pragma unroll
            for (int dx = 0; dx < 7; ++dx) {
                int xx = kx + dx - 3;
                if (xx < 0 || xx > 7) continue;
                v += clu_s[yy * 8 + xx][tid] * w[dy * 7 + dx];
            }
        }
        v += bias;
        float sv = v / (1.f + expf(-v));
        ref[((size_t)b * KK + k) * CCH + tid] = sv;
    }
}

// ---------- P2b: G[b,k,o] = sum_c refined * pw_w[o,c] + pw_b[o]; also G^T bf16 ----------
__global__ __launch_bounds__(256) void p2_g(const float* __restrict__ pw_b,
                                            float* __restrict__ ws) {
    __shared__ float rs[256];
    const int b = blockIdx.y, k = blockIdx.x, tid = threadIdx.x;
    const float* ref = ws + OFF_REF;
    const float* pwT = ws + OFF_PWT;
    float* G = ws + OFF_G;
    rs[tid] = ref[((size_t)b * KK + k) * CCH + tid];
    __syncthreads();
    float g = pw_b[tid];
#pragma unroll 8
    for (int c = 0; c < 256; ++c)
        g += rs[c] * pwT[c * CCH + tid];
    G[((size_t)b * KK + k) * CCH + tid] = g;
    ((unsigned short*)(ws + OFF_GT))[((size_t)b * CCH + tid) * KK + k] = f2bf(g);
}

// ---------- P2w: qpart[b,kq,c] = sum_{kk<8} W[kq*8+kk,c] * G[kq*8+kk,c] ----------
__global__ __launch_bounds__(256) void p2_w(float* __restrict__ ws) {
    __shared__ float Mrows[512];     // 8 k-rows of M, pre-scaled
    const int kq = blockIdx.x, b = blockIdx.y;
    const int tid = threadIdx.x;
#pragma unroll
    for (int it = 0; it < 2; ++it) {
        int idx = it * 256 + tid;    // 0..511
        Mrows[idx] = ws[OFF_MS2 + (size_t)b * 4096 + kq * 512 + idx] * (1.0f / 16384.0f);
    }
    __syncthreads();
    const float* G = ws + OFF_G + (size_t)b * KK * CCH;
    float t0 = 0.f, t1 = 0.f, t2 = 0.f, t3 = 0.f;
    float t4 = 0.f, t5 = 0.f, t6 = 0.f, t7 = 0.f;
#pragma unroll 8
    for (int k2 = 0; k2 < 64; ++k2) {
        float g = G[k2 * CCH + tid];
        t0 += Mrows[0 * 64 + k2] * g;
        t1 += Mrows[1 * 64 + k2] * g;
        t2 += Mrows[2 * 64 + k2] * g;
        t3 += Mrows[3 * 64 + k2] * g;
        t4 += Mrows[4 * 64 + k2] * g;
        t5 += Mrows[5 * 64 + k2] * g;
        t6 += Mrows[6 * 64 + k2] * g;
        t7 += Mrows[7 * 64 + k2] * g;
    }
    const float* Gk = G + (size_t)(kq * 8) * CCH + tid;
    float qp = t0 * Gk[0 * CCH] + t1 * Gk[1 * CCH] + t2 * Gk[2 * CCH] + t3 * Gk[3 * CCH]
             + t4 * Gk[4 * CCH] + t5 * Gk[5 * CCH] + t6 * Gk[6 * CCH] + t7 * Gk[7 * CCH];
    ws[OFF_QP + (size_t)(b * 8 + kq) * CCH + tid] = qp;
}

// ---------- P2c: group-norm statistics (mu from G stream, q from qpart) ----------
__global__ __launch_bounds__(256) void p2_stats(float* __restrict__ ws) {
    __shared__ float abs_[64];
    __shared__ float mu_s[256];
    __shared__ float q_s[256];
    const int b = blockIdx.x, tid = threadIdx.x;
    if (tid < 64)
        abs_[tid] = ws[OFF_ABS2 + b * KK + tid] * (1.0f / 16384.0f);
    __syncthreads();

    const float* G = ws + OFF_G + (size_t)b * KK * CCH;
    float mu = 0.f;
#pragma unroll 8
    for (int k = 0; k < 64; ++k)
        mu += abs_[k] * G[(size_t)k * CCH + tid];
    const float* qp = ws + OFF_QP + (size_t)b * 8 * CCH + tid;
    float q = 0.f;
#pragma unroll
    for (int kq = 0; kq < 8; ++kq)
        q += qp[(size_t)kq * CCH];
    mu_s[tid] = mu;
    q_s[tid] = q;
    __syncthreads();
    if (tid < 32) {
        float m = 0.f, e = 0.f;
#pragma unroll
        for (int j = 0; j < 8; ++j) { m += mu_s[tid * 8 + j]; e += q_s[tid * 8 + j]; }
        m *= 0.125f; e *= 0.125f;
        float var = e - m * m;
        ws[OFF_MU + b * 32 + tid] = m;
        ws[OFF_RS + b * 32 + tid] = rsqrtf(fmaxf(var, 0.f) + 1e-5f);
    }
}

// ---------- P3: y = attn @ G via MFMA ; out = x + (y-mu)*rsig*gamma + beta ----------
// GT fragments loaded direct global->reg (L2-hot); only attn staged in LDS (8 KB).
__global__ __launch_bounds__(256, 3) void p3_out(const float* __restrict__ x,
                                                 const float* __restrict__ gamma,
                                                 const float* __restrict__ beta,
                                                 const float* __restrict__ ws,
                                                 float* __restrict__ out) {
    __shared__ __align__(16) unsigned char sm3[8192];
    // attn tile bf16 [64 n][64 k], byte ^= ((n&7)<<4)
    const int tid = threadIdx.x;
    const int w  = tid >> 6;
    const int l  = tid & 63;
    const int lr = l & 15;
    const int lg = l >> 4;
    const int n0 = blockIdx.x * 64;
    const int b  = blockIdx.y;

    const unsigned short* attn_bf = (const unsigned short*)(ws + OFF_ATTN);
    const unsigned short* GTb = (const unsigned short*)(ws + OFF_GT) + (size_t)b * CCH * KK;

    // GT fragments: issue before the LDS barrier (hide L2 latency under staging)
    bf16x8 bg0[4], bg1[4];
#pragma unroll
    for (int ot = 0; ot < 4; ++ot) {
        const int o = w * 64 + ot * 16 + lr;
        bg0[ot] = *(const bf16x8*)(GTb + (size_t)o * KK + 0 * 32 + lg * 8);
        bg1[ot] = *(const bf16x8*)(GTb + (size_t)o * KK + 1 * 32 + lg * 8);
    }

    {
        const uint4* asrc = (const uint4*)(attn_bf + ((size_t)b * NN + n0) * KK);
#pragma unroll
        for (int it = 0; it < 2; ++it) {
            int flat = it * 256 + tid;
            int n = flat >> 3, c16 = flat & 7;
            *(uint4*)(sm3 + ((n * 128 + c16 * 16) ^ ((n & 7) << 4))) = asrc[n * 8 + c16];
        }
    }
    __syncthreads();

    f32x4 acc[4][4] = {};   // [nt][ot]
#pragma unroll
    for (int kh = 0; kh < 2; ++kh) {
        bf16x8 af[4];
#pragma unroll
        for (int nt = 0; nt < 4; ++nt) {
            int n = nt * 16 + lr;
            af[nt] = *(const bf16x8*)(sm3 + ((n * 128 + (kh * 64 + lg * 16)) ^ ((n & 7) << 4)));
        }
#pragma unroll
        for (int nt = 0; nt < 4; ++nt)
#pragma unroll
            for (int ot = 0; ot < 4; ++ot)
                acc[nt][ot] = MFMA16(af[nt], kh ? bg1[ot] : bg0[ot], acc[nt][ot], 0, 0, 0);
    }

#pragma unroll
    for (int ot = 0; ot < 4; ++ot) {
        const int o = w * 64 + ot * 16 + lr;
        const int grp = o >> 3;
        const float m = ws[OFF_MU + b * 32 + grp];
        const float r = ws[OFF_RS + b * 32 + grp];
        const float gm = gamma[o] * r;
        const float bt = beta[o];
#pragma unroll
        for (int nt = 0; nt < 4; ++nt) {
            const int n = n0 + nt * 16 + lg * 4;
            size_t base = ((size_t)(b * CCH + o)) * NN + n;
            float4 xv = *(const float4*)&x[base];
            f32x4 a = acc[nt][ot];
            float4 ov;
            ov.x = xv.x + (a[0] - m) * gm + bt;
            ov.y = xv.y + (a[1] - m) * gm + bt;
            ov.z = xv.z + (a[2] - m) * gm + bt;
            ov.w = xv.w + (a[3] - m) * gm + bt;
            *(float4*)&out[base] = ov;
        }
    }
}

extern "C" void kernel_launch(void* const* d_in, const int* in_sizes, int n_in,
                              void* d_out, int out_size, void* d_ws, size_t ws_size,
                              hipStream_t stream) {
    (void)in_sizes; (void)n_in; (void)out_size; (void)ws_size;
    const float* x       = (const float*)d_in[0];
    const float* centers = (const float*)d_in[1];
    const float* dw_w    = (const float*)d_in[2];
    const float* dw_b    = (const float*)d_in[3];
    const float* pw_w    = (const float*)d_in[4];
    const float* pw_b    = (const float*)d_in[5];
    const float* gn_g    = (const float*)d_in[6];
    const float* gn_b    = (const float*)d_in[7];
    float* out = (float*)d_out;
    float* ws  = (float*)d_ws;

    p0_prep<<<256, 256, 0, stream>>>(centers, pw_w, ws);
    p1_attn<<<dim3(64, 8), 256, 0, stream>>>(x, ws);
    p15_reduce<<<576, 256, 0, stream>>>(ws);
    p2_dw<<<dim3(4, 8), 256, 0, stream>>>(dw_w, dw_b, ws);
    p2_g<<<dim3(64, 8), 256, 0, stream>>>(pw_b, ws);
    p2_w<<<dim3(8, 8), 256, 0, stream>>>(ws);
    p2_stats<<<8, 256, 0, stream>>>(ws);
    p3_out<<<dim3(256, 8), 256, 0, stream>>>(x, gn_g, gn_b, ws, out);
}

// Round 13
// 337.788 us; speedup vs baseline: 1.1106x; 1.0255x over previous
//
#include <hip/hip_runtime.h>
#include <math.h>

#define BB 8
#define CCH 256
#define NN 16384
#define KK 64
#define SEGS 64        // 64 segments x 256 n

typedef __attribute__((ext_vector_type(8))) short bf16x8;
typedef __attribute__((ext_vector_type(4))) float f32x4;
#define MFMA16 __builtin_amdgcn_mfma_f32_16x16x32_bf16

// ---------------- workspace layout (float-slot offsets) ----------------
constexpr size_t OFF_ATTN = 0;                        // bf16 B*N*K  = 4194304 slots
constexpr size_t OFF_CTT  = 4194304;                  // bf16 K*C    = 8192 slots (16384 reserved)
constexpr size_t OFF_PWT  = 4210688;                  // f32 C*C     = 65536
constexpr size_t OFF_GT   = 4276224;                  // bf16 B*C*K  = 65536 slots
constexpr size_t OFF_CLUP = 4341760;                  // bf16 SEGS*B*K*C = 4194304 slots
constexpr size_t OFF_MP   = 8536064;                  // bf16 SEGS*B*K*K = 1048576 slots
constexpr size_t OFF_ABP  = 9584640;                  // f32 SEGS*B*K = 32768
constexpr size_t OFF_CLUS = 9617408;                  // f32 B*K*C    = 131072
constexpr size_t OFF_MS2  = 9748480;                  // f32 B*K*K    = 32768
constexpr size_t OFF_ABS2 = 9781248;                  // f32 B*K      = 512
constexpr size_t OFF_QP   = 9781760;                  // f32 B*8*C    = 16384
// CLUP region is dead after p15 -> reuse for post-reduce buffers:
constexpr size_t OFF_G    = OFF_CLUP + 131072;        // f32 B*K*C
constexpr size_t OFF_MU   = OFF_CLUP + 262144;        // f32 B*32
constexpr size_t OFF_RS   = OFF_CLUP + 262400;        // f32 B*32
// total = 9,798,144 slots = 39.2 MB

__device__ __forceinline__ unsigned short f2bf(float f) {
    unsigned int x = __float_as_uint(f);
    unsigned int r = (x + 0x7FFFu + ((x >> 16) & 1u)) >> 16;
    return (unsigned short)r;
}
__device__ __forceinline__ float bf2f(unsigned short u) {
    return __uint_as_float(((unsigned int)u) << 16);
}

// ---------- P0: centers -> bf16 (scale 2^-4 folded, exact), transpose pw_w ----------
__global__ __launch_bounds__(256) void p0_prep(const float* __restrict__ centers,
                                               const float* __restrict__ pw_w,
                                               float* __restrict__ ws) {
    int idx = blockIdx.x * 256 + threadIdx.x;   // 0..65535
    if (idx < 16384)
        ((unsigned short*)(ws + OFF_CTT))[idx] = f2bf(centers[idx] * 0.0625f);
    int c = idx >> 8, o = idx & 255;
    ws[OFF_PWT + idx] = pw_w[o * CCH + c];
}

// ---------- P1: MFMA sim -> softmax(shfl) -> attn(bf16) ; MFMA cluster/M ----------
// R10-exact (best measured). SEGS=64, LDS 59392, bounds(256,2).
__global__ __launch_bounds__(256, 2) void p1_attn(const float* __restrict__ x,
                                                  float* __restrict__ ws) {
    __shared__ __align__(16) unsigned char smem[59392];
    // [0,32768): xs bf16 [256][64], byte ^= ((c&7)<<4) swizzle ; epilogue: CLUP staging
    unsigned short* xTh = (unsigned short*)(smem + 32768); // bf16 [64][136] (c-half)
    float*          S   = (float*)(smem + 32768);          // f32 [64][68] overlay
    unsigned short* aT  = (unsigned short*)(smem + 50176); // bf16 [64][72] attn^T
    float*          scr = (float*)(smem + 50176);          // abar scratch (aT dead)

    const int tid = threadIdx.x;
    const int w  = tid >> 6;       // wave 0..3
    const int l  = tid & 63;
    const int lr = l & 15;
    const int lg = l >> 4;
    const int b   = blockIdx.y;
    const int seg = blockIdx.x;    // 0..63
    const int cstage = tid >> 4;   // 0..15
    const int n4     = tid & 15;

    const unsigned short* ctb = (const unsigned short*)(ws + OFF_CTT);
    unsigned short* attn_bf = (unsigned short*)(ws + OFF_ATTN);

    bf16x8 bc[8];
#pragma unroll
    for (int cs = 0; cs < 8; ++cs)
        bc[cs] = *(const bf16x8*)(ctb + (w * 16 + lr) * CCH + cs * 32 + lg * 8);

    f32x4 cacc[4][4] = {};   // cluster [kt][ct], c-strip = w*64..
    f32x4 macc[4]    = {};   // M [k1t], k2-strip = w*16..
    float ab_acc = 0.f;

    float4 v[8];
    {   // preload sub0 half0
#pragma unroll
        for (int it = 0; it < 8; ++it) {
            int c = it * 16 + cstage;
            v[it] = *(const float4*)&x[((size_t)(b * CCH + c)) * NN + seg * 256 + 4 * n4];
        }
    }

#pragma unroll 1
    for (int sub = 0; sub < 4; ++sub) {
        const int ns0 = seg * 256 + sub * 64;
        f32x4 sacc[4] = {};

#pragma unroll
        for (int h = 0; h < 2; ++h) {
            __syncthreads();   // prev consumers of xs/xTh done
#pragma unroll
            for (int it = 0; it < 8; ++it) {
                int c = h * 128 + it * 16 + cstage;
                int cl = c & 127;
                ushort4 bv;
                bv.x = f2bf(v[it].x); bv.y = f2bf(v[it].y);
                bv.z = f2bf(v[it].z); bv.w = f2bf(v[it].w);
                *(ushort4*)(smem + ((c * 128 + 8 * n4) ^ ((c & 7) << 4))) = bv;
                xTh[(4 * n4 + 0) * 136 + cl] = bv.x;
                xTh[(4 * n4 + 1) * 136 + cl] = bv.y;
                xTh[(4 * n4 + 2) * 136 + cl] = bv.z;
                xTh[(4 * n4 + 3) * 136 + cl] = bv.w;
            }
            if (!(sub == 3 && h == 1)) {
                const int nsub = sub + h;
                const int nh = h ^ 1;
                const int pns0 = seg * 256 + nsub * 64;
#pragma unroll
                for (int it = 0; it < 8; ++it) {
                    int c = nh * 128 + it * 16 + cstage;
                    v[it] = *(const float4*)&x[((size_t)(b * CCH + c)) * NN + pns0 + 4 * n4];
                }
            }
            __syncthreads();
#pragma unroll
            for (int cc = 0; cc < 4; ++cc) {
                const int co = cc * 32 + lg * 8;
                bf16x8 a0 = *(const bf16x8*)(xTh + (lr     ) * 136 + co);
                bf16x8 a1 = *(const bf16x8*)(xTh + (16 + lr) * 136 + co);
                bf16x8 a2 = *(const bf16x8*)(xTh + (32 + lr) * 136 + co);
                bf16x8 a3 = *(const bf16x8*)(xTh + (48 + lr) * 136 + co);
                bf16x8 bfr = bc[h * 4 + cc];
                sacc[0] = MFMA16(a0, bfr, sacc[0], 0, 0, 0);
                sacc[1] = MFMA16(a1, bfr, sacc[1], 0, 0, 0);
                sacc[2] = MFMA16(a2, bfr, sacc[2], 0, 0, 0);
                sacc[3] = MFMA16(a3, bfr, sacc[3], 0, 0, 0);
            }
        }
        __syncthreads();   // xTh reads done -> region becomes S
#pragma unroll
        for (int nt = 0; nt < 4; ++nt)
#pragma unroll
            for (int r = 0; r < 4; ++r)
                S[(nt * 16 + lg * 4 + r) * 68 + w * 16 + lr] = sacc[nt][r];
        __syncthreads();

        // ---- softmax: 4 lanes per row, shuffle reduce ----
        {
            const int rn = tid >> 2, q = tid & 3;
            float e[16];
#pragma unroll
            for (int m = 0; m < 4; ++m) {
                float4 vv = *(float4*)&S[rn * 68 + q * 16 + 4 * m];
                e[4*m+0] = vv.x; e[4*m+1] = vv.y; e[4*m+2] = vv.z; e[4*m+3] = vv.w;
            }
            float mx = -1e30f;
#pragma unroll
            for (int t = 0; t < 16; ++t) mx = fmaxf(mx, e[t]);
            mx = fmaxf(mx, __shfl_xor(mx, 1, 64));
            mx = fmaxf(mx, __shfl_xor(mx, 2, 64));
            float ls = 0.f;
#pragma unroll
            for (int t = 0; t < 16; ++t) { e[t] = __expf(e[t] - mx); ls += e[t]; }
            ls += __shfl_xor(ls, 1, 64);
            ls += __shfl_xor(ls, 2, 64);
            float rinv = 1.f / ls;
            unsigned short bt16[16];
#pragma unroll
            for (int t = 0; t < 16; ++t) {
                bt16[t] = f2bf(e[t] * rinv);
                aT[(q * 16 + t) * 72 + rn] = bt16[t];
            }
            unsigned int* gdst = (unsigned int*)(attn_bf + ((size_t)b * NN + ns0 + rn) * KK + q * 16);
            uint4 pk0, pk1;
            pk0.x = (unsigned int)bt16[0]  | ((unsigned int)bt16[1]  << 16);
            pk0.y = (unsigned int)bt16[2]  | ((unsigned int)bt16[3]  << 16);
            pk0.z = (unsigned int)bt16[4]  | ((unsigned int)bt16[5]  << 16);
            pk0.w = (unsigned int)bt16[6]  | ((unsigned int)bt16[7]  << 16);
            pk1.x = (unsigned int)bt16[8]  | ((unsigned int)bt16[9]  << 16);
            pk1.y = (unsigned int)bt16[10] | ((unsigned int)bt16[11] << 16);
            pk1.z = (unsigned int)bt16[12] | ((unsigned int)bt16[13] << 16);
            pk1.w = (unsigned int)bt16[14] | ((unsigned int)bt16[15] << 16);
            *(uint4*)gdst = pk0;
            *(uint4*)(gdst + 4) = pk1;
        }
        __syncthreads();   // aT ready

        // ---- abar partial ----
        {
            const int kk = tid & 63;
#pragma unroll
            for (int m = 0; m < 4; ++m) {
                ushort4 av = *(const ushort4*)(aT + kk * 72 + w * 16 + 4 * m);
                ab_acc += bf2f(av.x) + bf2f(av.y) + bf2f(av.z) + bf2f(av.w);
            }
        }
        // ---- M partial ----
#pragma unroll
        for (int s = 0; s < 2; ++s) {
            const int no = s * 32 + lg * 8;
            bf16x8 am = *(const bf16x8*)(aT + (w * 16 + lr) * 72 + no);
#pragma unroll
            for (int k1t = 0; k1t < 4; ++k1t) {
                bf16x8 bm = *(const bf16x8*)(aT + (k1t * 16 + lr) * 72 + no);
                macc[k1t] = MFMA16(am, bm, macc[k1t], 0, 0, 0);
            }
        }
        // ---- CLU partial ----
#pragma unroll
        for (int s = 0; s < 2; ++s) {
            const int no = s * 32 + lg * 8;
            bf16x8 aa0 = *(const bf16x8*)(aT + (lr     ) * 72 + no);
            bf16x8 aa1 = *(const bf16x8*)(aT + (16 + lr) * 72 + no);
            bf16x8 aa2 = *(const bf16x8*)(aT + (32 + lr) * 72 + no);
            bf16x8 aa3 = *(const bf16x8*)(aT + (48 + lr) * 72 + no);
#pragma unroll
            for (int ct = 0; ct < 4; ++ct) {
                const int c = w * 64 + ct * 16 + lr;
                bf16x8 bb = *(const bf16x8*)(smem + ((c * 128 + no * 2) ^ ((c & 7) << 4)));
                cacc[0][ct] = MFMA16(aa0, bb, cacc[0][ct], 0, 0, 0);
                cacc[1][ct] = MFMA16(aa1, bb, cacc[1][ct], 0, 0, 0);
                cacc[2][ct] = MFMA16(aa2, bb, cacc[2][ct], 0, 0, 0);
                cacc[3][ct] = MFMA16(aa3, bb, cacc[3][ct], 0, 0, 0);
            }
        }
    }

    // ---- epilogue: stage CLUP (bf16, xs region) + M (S region) + abar (scr) ----
    __syncthreads();   // all xs/aT/S reads complete
    {
        unsigned short* stg = (unsigned short*)smem;   // [64 k][256 c], c ^= ((k&7)<<3)
#pragma unroll
        for (int kt = 0; kt < 4; ++kt)
#pragma unroll
            for (int ct = 0; ct < 4; ++ct) {
                const int c = w * 64 + ct * 16 + lr;
#pragma unroll
                for (int r = 0; r < 4; ++r) {
                    const int row = kt * 16 + lg * 4 + r;
                    stg[row * 256 + (c ^ ((row & 7) << 3))] = f2bf(cacc[kt][ct][r]);
                }
            }
    }
#pragma unroll
    for (int k1t = 0; k1t < 4; ++k1t)
#pragma unroll
        for (int r = 0; r < 4; ++r)
            S[(w * 16 + lg * 4 + r) * 68 + k1t * 16 + lr] = macc[k1t][r];
    scr[(tid & 63) * 4 + (tid >> 6)] = ab_acc;
    __syncthreads();
    // ---- coalesced global writes ----
    {
        uint4* gb = (uint4*)((unsigned short*)(ws + OFF_CLUP) + (size_t)(seg * BB + b) * 16384);
        const uint4* s4 = (const uint4*)smem;
#pragma unroll
        for (int it = 0; it < 8; ++it) {
            int f = it * 256 + tid;                    // 0..2047
            gb[f] = s4[(f >> 5) * 32 + ((f & 31) ^ ((f >> 5) & 7))];
        }
    }
    {
        unsigned int* mp32 = (unsigned int*)((unsigned short*)(ws + OFF_MP) + (size_t)(seg * BB + b) * 4096);
#pragma unroll
        for (int it = 0; it < 8; ++it) {
            int flat = it * 256 + tid;                 // 0..2047
            int k2 = flat >> 5, kp = flat & 31;
            unsigned int pv = (unsigned int)f2bf(S[k2 * 68 + 2 * kp])
                            | ((unsigned int)f2bf(S[k2 * 68 + 2 * kp + 1]) << 16);
            mp32[flat] = pv;
        }
    }
    if (tid < 64)
        ws[OFF_ABP + (size_t)(seg * BB + b) * KK + tid] =
            scr[tid * 4 + 0] + scr[tid * 4 + 1] + scr[tid * 4 + 2] + scr[tid * 4 + 3];
}

// ---------- P1.5: reduce partials over 64 segs ----------
__global__ __launch_bounds__(256) void p15_reduce(float* __restrict__ ws) {
    const int blk = blockIdx.x;
    if (blk < 512) {
        const int b = blk >> 6, k = blk & 63, c = threadIdx.x;
        const unsigned short* clu_p = (const unsigned short*)(ws + OFF_CLUP);
        float s = 0.f;
#pragma unroll 8
        for (int seg = 0; seg < SEGS; ++seg)
            s += bf2f(clu_p[((size_t)((seg * BB + b) * KK + k)) * CCH + c]);
        ws[OFF_CLUS + ((size_t)(b * KK + k)) * CCH + c] = s;
    } else {
        const int t = blk - 512;
        const int b = t >> 3, part = t & 7;
        const unsigned short* m_p = (const unsigned short*)(ws + OFF_MP);
#pragma unroll
        for (int it = 0; it < 2; ++it) {
            int idx = part * 512 + it * 256 + threadIdx.x;
            float s = 0.f;
#pragma unroll 8
            for (int seg = 0; seg < SEGS; ++seg)
                s += bf2f(m_p[(size_t)(seg * BB + b) * 4096 + idx]);
            ws[OFF_MS2 + (size_t)b * 4096 + idx] = s;
        }
        if (part == 0 && threadIdx.x < 64) {
            float s = 0.f;
#pragma unroll 8
            for (int seg = 0; seg < SEGS; ++seg)
                s += ws[OFF_ABP + (size_t)(seg * BB + b) * KK + threadIdx.x];
            ws[OFF_ABS2 + b * KK + threadIdx.x] = s;
        }
    }
}

// ---------- P2a+b fused: dw7x7+silu from CLUS (LDS) then G row + GT bf16 ----------
// grid (64 k, 8 b). CLUS per b = 64 KB, staged in LDS; re-reads across the 64
// blocks sharing b are L2-hits. Removes REF write+read (8 MB) and one launch.
__global__ __launch_bounds__(256) void p2_dwg(const float* __restrict__ dw_w,
                                              const float* __restrict__ dw_b,
                                              const float* __restrict__ pw_b,
                                              float* __restrict__ ws) {
    __shared__ float clu_s[64][256];   // 64 KB
    __shared__ float rs[256];
    const int b = blockIdx.y, k = blockIdx.x, tid = threadIdx.x;
    for (int kk = 0; kk < 64; ++kk)
        clu_s[kk][tid] = ws[OFF_CLUS + ((size_t)(b * KK + kk)) * CCH + tid];
    __syncthreads();

    // depthwise 7x7 + bias + silu for this k, channel c=tid (identical math to p2_dw)
    {
        const int ky = k >> 3, kx = k & 7;
        float v = 0.f;
#pragma unroll
        for (int dy = 0; dy < 7; ++dy) {
            int yy = ky + dy - 3;
            if (yy < 0 || yy > 7) continue;
#pragma unroll
            for (int dx = 0; dx < 7; ++dx) {
                int xx = kx + dx - 3;
                if (xx < 0 || xx > 7) continue;
                v += clu_s[yy * 8 + xx][tid] * dw_w[tid * 49 + dy * 7 + dx];
            }
        }
        v += dw_b[tid];
        rs[tid] = v / (1.f + expf(-v));
    }
    __syncthreads();

    // G[b,k,o] = sum_c rs[c] * pwT[c][o] + pw_b[o] ; also GT bf16
    const float* pwT = ws + OFF_PWT;
    float* G = ws + OFF_G;
    float g = pw_b[tid];
#pragma unroll 8
    for (int c = 0; c < 256; ++c)
        g += rs[c] * pwT[c * CCH + tid];
    G[((size_t)b * KK + k) * CCH + tid] = g;
    ((unsigned short*)(ws + OFF_GT))[((size_t)b * CCH + tid) * KK + k] = f2bf(g);
}

// ---------- P2w: qpart[b,kq,c] = sum_{kk<8} W[kq*8+kk,c] * G[kq*8+kk,c] ----------
__global__ __launch_bounds__(256) void p2_w(float* __restrict__ ws) {
    __shared__ float Mrows[512];     // 8 k-rows of M, pre-scaled
    const int kq = blockIdx.x, b = blockIdx.y;
    const int tid = threadIdx.x;
#pragma unroll
    for (int it = 0; it < 2; ++it) {
        int idx = it * 256 + tid;    // 0..511
        Mrows[idx] = ws[OFF_MS2 + (size_t)b * 4096 + kq * 512 + idx] * (1.0f / 16384.0f);
    }
    __syncthreads();
    const float* G = ws + OFF_G + (size_t)b * KK * CCH;
    float t0 = 0.f, t1 = 0.f, t2 = 0.f, t3 = 0.f;
    float t4 = 0.f, t5 = 0.f, t6 = 0.f, t7 = 0.f;
#pragma unroll 8
    for (int k2 = 0; k2 < 64; ++k2) {
        float g = G[k2 * CCH + tid];
        t0 += Mrows[0 * 64 + k2] * g;
        t1 += Mrows[1 * 64 + k2] * g;
        t2 += Mrows[2 * 64 + k2] * g;
        t3 += Mrows[3 * 64 + k2] * g;
        t4 += Mrows[4 * 64 + k2] * g;
        t5 += Mrows[5 * 64 + k2] * g;
        t6 += Mrows[6 * 64 + k2] * g;
        t7 += Mrows[7 * 64 + k2] * g;
    }
    const float* Gk = G + (size_t)(kq * 8) * CCH + tid;
    float qp = t0 * Gk[0 * CCH] + t1 * Gk[1 * CCH] + t2 * Gk[2 * CCH] + t3 * Gk[3 * CCH]
             + t4 * Gk[4 * CCH] + t5 * Gk[5 * CCH] + t6 * Gk[6 * CCH] + t7 * Gk[7 * CCH];
    ws[OFF_QP + (size_t)(b * 8 + kq) * CCH + tid] = qp;
}

// ---------- P2c: group-norm statistics (mu from G stream, q from qpart) ----------
__global__ __launch_bounds__(256) void p2_stats(float* __restrict__ ws) {
    __shared__ float abs_[64];
    __shared__ float mu_s[256];
    __shared__ float q_s[256];
    const int b = blockIdx.x, tid = threadIdx.x;
    if (tid < 64)
        abs_[tid] = ws[OFF_ABS2 + b * KK + tid] * (1.0f / 16384.0f);
    __syncthreads();

    const float* G = ws + OFF_G + (size_t)b * KK * CCH;
    float mu = 0.f;
#pragma unroll 8
    for (int k = 0; k < 64; ++k)
        mu += abs_[k] * G[(size_t)k * CCH + tid];
    const float* qp = ws + OFF_QP + (size_t)b * 8 * CCH + tid;
    float q = 0.f;
#pragma unroll
    for (int kq = 0; kq < 8; ++kq)
        q += qp[(size_t)kq * CCH];
    mu_s[tid] = mu;
    q_s[tid] = q;
    __syncthreads();
    if (tid < 32) {
        float m = 0.f, e = 0.f;
#pragma unroll
        for (int j = 0; j < 8; ++j) { m += mu_s[tid * 8 + j]; e += q_s[tid * 8 + j]; }
        m *= 0.125f; e *= 0.125f;
        float var = e - m * m;
        ws[OFF_MU + b * 32 + tid] = m;
        ws[OFF_RS + b * 32 + tid] = rsqrtf(fmaxf(var, 0.f) + 1e-5f);
    }
}

// ---------- P3: y = attn @ G via MFMA ; out = x + (y-mu)*rsig*gamma + beta ----------
// GT fragments loaded direct global->reg (L2-hot); only attn staged in LDS (8 KB).
__global__ __launch_bounds__(256, 3) void p3_out(const float* __restrict__ x,
                                                 const float* __restrict__ gamma,
                                                 const float* __restrict__ beta,
                                                 const float* __restrict__ ws,
                                                 float* __restrict__ out) {
    __shared__ __align__(16) unsigned char sm3[8192];
    // attn tile bf16 [64 n][64 k], byte ^= ((n&7)<<4)
    const int tid = threadIdx.x;
    const int w  = tid >> 6;
    const int l  = tid & 63;
    const int lr = l & 15;
    const int lg = l >> 4;
    const int n0 = blockIdx.x * 64;
    const int b  = blockIdx.y;

    const unsigned short* attn_bf = (const unsigned short*)(ws + OFF_ATTN);
    const unsigned short* GTb = (const unsigned short*)(ws + OFF_GT) + (size_t)b * CCH * KK;

    // GT fragments: issue before the LDS barrier (hide L2 latency under staging)
    bf16x8 bg0[4], bg1[4];
#pragma unroll
    for (int ot = 0; ot < 4; ++ot) {
        const int o = w * 64 + ot * 16 + lr;
        bg0[ot] = *(const bf16x8*)(GTb + (size_t)o * KK + 0 * 32 + lg * 8);
        bg1[ot] = *(const bf16x8*)(GTb + (size_t)o * KK + 1 * 32 + lg * 8);
    }

    {
        const uint4* asrc = (const uint4*)(attn_bf + ((size_t)b * NN + n0) * KK);
#pragma unroll
        for (int it = 0; it < 2; ++it) {
            int flat = it * 256 + tid;
            int n = flat >> 3, c16 = flat & 7;
            *(uint4*)(sm3 + ((n * 128 + c16 * 16) ^ ((n & 7) << 4))) = asrc[n * 8 + c16];
        }
    }
    __syncthreads();

    f32x4 acc[4][4] = {};   // [nt][ot]
#pragma unroll
    for (int kh = 0; kh < 2; ++kh) {
        bf16x8 af[4];
#pragma unroll
        for (int nt = 0; nt < 4; ++nt) {
            int n = nt * 16 + lr;
            af[nt] = *(const bf16x8*)(sm3 + ((n * 128 + (kh * 64 + lg * 16)) ^ ((n & 7) << 4)));
        }
#pragma unroll
        for (int nt = 0; nt < 4; ++nt)
#pragma unroll
            for (int ot = 0; ot < 4; ++ot)
                acc[nt][ot] = MFMA16(af[nt], kh ? bg1[ot] : bg0[ot], acc[nt][ot], 0, 0, 0);
    }

#pragma unroll
    for (int ot = 0; ot < 4; ++ot) {
        const int o = w * 64 + ot * 16 + lr;
        const int grp = o >> 3;
        const float m = ws[OFF_MU + b * 32 + grp];
        const float r = ws[OFF_RS + b * 32 + grp];
        const float gm = gamma[o] * r;
        const float bt = beta[o];
#pragma unroll
        for (int nt = 0; nt < 4; ++nt) {
            const int n = n0 + nt * 16 + lg * 4;
            size_t base = ((size_t)(b * CCH + o)) * NN + n;
            float4 xv = *(const float4*)&x[base];
            f32x4 a = acc[nt][ot];
            float4 ov;
            ov.x = xv.x + (a[0] - m) * gm + bt;
            ov.y = xv.y + (a[1] - m) * gm + bt;
            ov.z = xv.z + (a[2] - m) * gm + bt;
            ov.w = xv.w + (a[3] - m) * gm + bt;
            *(float4*)&out[base] = ov;
        }
    }
}

extern "C" void kernel_launch(void* const* d_in, const int* in_sizes, int n_in,
                              void* d_out, int out_size, void* d_ws, size_t ws_size,
                              hipStream_t stream) {
    (void)in_sizes; (void)n_in; (void)out_size; (void)ws_size;
    const float* x       = (const float*)d_in[0];
    const float* centers = (const float*)d_in[1];
    const float* dw_w    = (const float*)d_in[2];
    const float* dw_b    = (const float*)d_in[3];
    const float* pw_w    = (const float*)d_in[4];
    const float* pw_b    = (const float*)d_in[5];
    const float* gn_g    = (const float*)d_in[6];
    const float* gn_b    = (const float*)d_in[7];
    float* out = (float*)d_out;
    float* ws  = (float*)d_ws;

    p0_prep<<<256, 256, 0, stream>>>(centers, pw_w, ws);
    p1_attn<<<dim3(64, 8), 256, 0, stream>>>(x, ws);
    p15_reduce<<<576, 256, 0, stream>>>(ws);
    p2_dwg<<<dim3(64, 8), 256, 0, stream>>>(dw_w, dw_b, pw_b, ws);
    p2_w<<<dim3(8, 8), 256, 0, stream>>>(ws);
    p2_stats<<<8, 256, 0, stream>>>(ws);
    p3_out<<<dim3(256, 8), 256, 0, stream>>>(x, gn_g, gn_b, ws, out);
}